// Round 3
// baseline (163.396 us; speedup 1.0000x reference)
//
#include <hip/hip_runtime.h>

#define G_ 100
#define T_ 24
#define GP1 101
#define TILE (G_ * T_)        // 2400 floats per (b,pass) tile
#define VPB (TILE / 4)        // 600 float4 per tile
#define BPB 4                 // b's per block
#define WPB (BPB * 2)         // 8 waves: 4 b's x 2 passes
#define BLOCK (64 * WPB)      // 512 threads

typedef float vfloat4 __attribute__((ext_vector_type(4)));

// Merit-order chunk: batch N 96B-row cap loads (each inst: 24 lanes ->
// 96 contiguous bytes = 2 lines, coalesced), serial clip-scan, allocs
// stored directly to the global output row. Each row is written EXACTLY
// once kernel-wide (scan rows here, untouched rows by the tail-zero
// loop), so no store-order fence is needed anywhere.
// ord/price come from per-wave registers via v_readlane (uniform -> SGPR,
// exec-mask-ignoring, safe under the lane<24 divergent branch).
template<int N>
__device__ __forceinline__ void scan_chunk(int k0,
    const float* __restrict__ capp,          // R_p[b] + t (per-lane)
    float* __restrict__ gcol,                // out tile + t (per-lane)
    int ord_lo, int ord_hi, float pr_lo, float pr_hi,
    float dem, float& before, float& objp)
{
    int gg[N]; float pr[N], cap[N];
#pragma unroll
    for (int j = 0; j < N; ++j) {
        const int idx = k0 + j;              // compile-time constant
        if (idx < 64) {
            gg[j] = __builtin_amdgcn_readlane(ord_lo, idx);
            pr[j] = __int_as_float(__builtin_amdgcn_readlane(__float_as_int(pr_lo), idx));
        } else {
            gg[j] = __builtin_amdgcn_readlane(ord_hi, idx - 64);
            pr[j] = __int_as_float(__builtin_amdgcn_readlane(__float_as_int(pr_hi), idx - 64));
        }
    }
#pragma unroll
    for (int j = 0; j < N; ++j) cap[j] = capp[gg[j] * T_];   // N loads in flight
#pragma unroll
    for (int j = 0; j < N; ++j) {
        float a = fminf(fmaxf(dem - before, 0.f), cap[j]);
        before += cap[j];
        objp = fmaf(pr[j], a, objp);
        gcol[gg[j] * T_] = a;                // single write, own row
    }
}

__global__ __launch_bounds__(BLOCK, 8) void dispatch_kernel(
    const float* __restrict__ R_up, const float* __restrict__ R_dn,
    const float* __restrict__ omega,
    const float* __restrict__ b_G, const float* __restrict__ voll,
    const float* __restrict__ vosp, const float* __restrict__ ru,
    const float* __restrict__ rd,
    float* __restrict__ out, int B)
{
    // tiny LDS only: sort scratch + obj pairing -> occupancy is wave-limited
    __shared__ float s_praw[2][GP1];
    __shared__ int   s_ord [2][128];
    __shared__ float s_pr  [2][128];
    __shared__ float s_obj [WPB];

    const int tid = threadIdx.x;

    // ---- fused merit-order sort (== stable jnp.argsort of prices) ----
    if (tid < GP1) {
        float mu, md;
        if (tid < G_) { float bg = b_G[tid]; mu = ru[0] * bg; md = rd[0] * bg; }
        else          { mu = voll[0];        md = vosp[0]; }
        s_praw[0][tid] = mu; s_praw[1][tid] = md;
    }
    __syncthreads();
    {   // up-ranks on threads [0,101), dn-ranks on threads [256,357) (parallel waves)
        const int pass = tid >> 8;
        const int i    = tid & 255;
        if (i < GP1) {
            const float m = s_praw[pass][i];
            int r = 0;
            for (int j = 0; j < GP1; ++j) {
                const float v = s_praw[pass][j];
                r += (v < m) || (v == m && j < i);
            }
            s_ord[pass][r] = i;  s_pr[pass][r] = m;
        }
    }
    __syncthreads();

    const int w    = tid >> 6;
    const int lane = tid & 63;
    const int b = __builtin_amdgcn_readfirstlane(blockIdx.x * BPB + (w >> 1));
    const int p = __builtin_amdgcn_readfirstlane(w & 1);
    const size_t bgt = (size_t)B * TILE;

    // cache this wave's sorted merit order in registers
    const int hi_ok = (lane < GP1 - 64);
    const int   ord_lo = s_ord[p][lane];
    const int   ord_hi = hi_ok ? s_ord[p][64 + lane] : 0;
    const float pr_lo  = s_pr [p][lane];
    const float pr_hi  = hi_ok ? s_pr [p][64 + lane] : 0.f;

    const int t = (lane < T_) ? lane : 0;    // scan lanes: 0..23

    float objp = 0.f;
    if (lane < T_) {
        const float om  = omega[(size_t)b * T_ + t];
        const float dem = p ? fmaxf(-om, 0.f) : fmaxf(om, 0.f);
        const float* __restrict__ capp = (p ? R_dn : R_up) + (size_t)b * TILE + t;
        float* __restrict__ gcol = out + (size_t)p * bgt + (size_t)b * TILE + t;

        float before = 0.f;
        // ranks 0..31 unconditional, back-to-back: all 32 row loads are
        // independent (noalias) -> compiler hoists into one flight ->
        // one HBM latency round covers the typical k* (~25-35).
        scan_chunk<16>( 0, capp, gcol, ord_lo, ord_hi, pr_lo, pr_hi, dem, before, objp);
        scan_chunk<16>(16, capp, gcol, ord_lo, ord_hi, pr_lo, pr_hi, dem, before, objp);
        int K = 32;
        bool run = __any(before < dem);
        if (run) { scan_chunk<16>(32, capp, gcol, ord_lo, ord_hi, pr_lo, pr_hi, dem, before, objp);
                   K = 48; run = __any(before < dem); }
        if (run) { scan_chunk<16>(48, capp, gcol, ord_lo, ord_hi, pr_lo, pr_hi, dem, before, objp);
                   K = 64; run = __any(before < dem); }
        if (run) { scan_chunk< 8>(64, capp, gcol, ord_lo, ord_hi, pr_lo, pr_hi, dem, before, objp);
                   K = 72; run = __any(before < dem); }
        if (run) { scan_chunk< 8>(72, capp, gcol, ord_lo, ord_hi, pr_lo, pr_hi, dem, before, objp);
                   K = 80; run = __any(before < dem); }
        if (run) { scan_chunk< 8>(80, capp, gcol, ord_lo, ord_hi, pr_lo, pr_hi, dem, before, objp);
                   K = 88; run = __any(before < dem); }
        if (run) { scan_chunk< 8>(88, capp, gcol, ord_lo, ord_hi, pr_lo, pr_hi, dem, before, objp);
                   K = 96; run = __any(before < dem); }
        if (run) { scan_chunk< 4>(96, capp, gcol, ord_lo, ord_hi, pr_lo, pr_hi, dem, before, objp);
                   K = 100; }

        // tail-zero: rows ord[K..99] were never executed -> write their
        // zeros now (K is wave-uniform; v_readlane takes a runtime SGPR
        // index). Each row written exactly once kernel-wide -> no fence.
        for (int r = K; r < G_; ++r) {
            const int g = (r < 64) ? __builtin_amdgcn_readlane(ord_lo, r)
                                   : __builtin_amdgcn_readlane(ord_hi, r - 64);
            gcol[g * T_] = 0.f;
        }

        // slack (rank 100 == GP1-1): clip(dem - sum_all, 0, dem); early exit => 0.
        const float slack_pr =
            __int_as_float(__builtin_amdgcn_readlane(__float_as_int(pr_hi), GP1 - 1 - 64));
        float slackv = fmaxf(dem - before, 0.f);
        objp = fmaf(slack_pr, slackv, objp);
        out[2 * bgt + (size_t)p * B * T_ + (size_t)b * T_ + t] = slackv;
    }

    // ---- rt_obj partial: butterfly over the wave (idle lanes hold 0) ----
#pragma unroll
    for (int off = 32; off; off >>= 1) objp += __shfl_xor(objp, off, 64);
    if (lane == 0) s_obj[w] = objp;

    // ---- pair up+dn partials per b ----
    __syncthreads();
    if ((tid & 127) == 0)
        out[2 * bgt + 2 * (size_t)B * T_ + b] = s_obj[w] + s_obj[w + 1];
}

extern "C" void kernel_launch(void* const* d_in, const int* in_sizes, int n_in,
                              void* d_out, int out_size, void* d_ws, size_t ws_size,
                              hipStream_t stream)
{
    const float* R_up  = (const float*)d_in[0];
    const float* R_dn  = (const float*)d_in[1];
    const float* omega = (const float*)d_in[2];
    const float* b_G   = (const float*)d_in[3];
    const float* voll  = (const float*)d_in[4];
    const float* vosp  = (const float*)d_in[5];
    const float* ru    = (const float*)d_in[6];
    const float* rd    = (const float*)d_in[7];

    const int B = in_sizes[0] / TILE;
    float* out = (float*)d_out;

    // single fused launch: 8 waves/block = 4 b's x 2 passes; grid B/4
    dispatch_kernel<<<B / BPB, BLOCK, 0, stream>>>(
        R_up, R_dn, omega, b_G, voll, vosp, ru, rd, out, B);
}